// Round 1
// baseline (317.158 us; speedup 1.0000x reference)
//
#include <hip/hip_runtime.h>
#include <hip/hip_bf16.h>
#include <stdint.h>

#define D_DIM 256
#define INV_T 14.285714285714286f  // 1/0.07

#define BM 128
#define BN 128
#define BK 64

typedef __bf16 bf16x8 __attribute__((ext_vector_type(8)));
typedef float f32x4 __attribute__((ext_vector_type(4)));

// ---------------------------------------------------------------------------
// Kernel A: per-row normalization (fp32), exact fp32 diagonal Sv, bf16 outputs,
// and rowsum zero-init (harness poisons d_ws with 0xAA before every launch).
// One block (256 threads) per row; D == 256 == blockDim.
// ---------------------------------------------------------------------------
__global__ __launch_bounds__(256) void lit_normalize(
    const float* __restrict__ X, const float* __restrict__ Y,
    __hip_bfloat16* __restrict__ Xb, __hip_bfloat16* __restrict__ Yb,
    float* __restrict__ Sv, float* __restrict__ rowsum)
{
    int i = blockIdx.x;
    int t = threadIdx.x;
    size_t base = (size_t)i * D_DIM;
    float x = X[base + t];
    float y = Y[base + t];
    float nx = x * x, ny = y * y, dt = x * y;
    #pragma unroll
    for (int o = 32; o > 0; o >>= 1) {
        nx += __shfl_down(nx, o);
        ny += __shfl_down(ny, o);
        dt += __shfl_down(dt, o);
    }
    __shared__ float sred[3][4];
    int w = t >> 6;
    if ((t & 63) == 0) { sred[0][w] = nx; sred[1][w] = ny; sred[2][w] = dt; }
    __syncthreads();
    nx = sred[0][0] + sred[0][1] + sred[0][2] + sred[0][3];
    ny = sred[1][0] + sred[1][1] + sred[1][2] + sred[1][3];
    dt = sred[2][0] + sred[2][1] + sred[2][2] + sred[2][3];
    float nrx = fmaxf(sqrtf(nx), 1e-12f);
    float nry = fmaxf(sqrtf(ny), 1e-12f);
    float ivx = 1.0f / nrx, ivy = 1.0f / nry;
    Xb[base + t] = __float2bfloat16(x * ivx);
    Yb[base + t] = __float2bfloat16(y * ivy);
    if (t == 0) {
        Sv[i] = (dt * ivx * ivy - 1.0f) * INV_T;   // exact diagonal logit
        rowsum[i] = 0.0f;
    }
}

// ---------------------------------------------------------------------------
// Kernel B: S = Xhat @ Yhat^T in bf16 MFMA (16x16x32), fused
// exp((s-1)/tau) + row-sum epilogue. 128x128 tile, BK=64, 4 waves (2x2),
// each wave computes a 64x64 sub-tile (4x4 fragments).
// LDS layout: [row][slot] with slot XOR-swizzle (slot ^ (row&7)) realized by
// pre-swizzling the *global* source address so global_load_lds (linear dest,
// wave-uniform base + lane*16) lands the swizzled layout (guide rule #21).
// ---------------------------------------------------------------------------
__global__ __launch_bounds__(256) void lit_gemm_rowsum(
    const __hip_bfloat16* __restrict__ Xb, const __hip_bfloat16* __restrict__ Yb,
    float* __restrict__ rowsum, int N)
{
    __shared__ char lds[2 * BM * BK * 2];  // 16KB A + 16KB B
    char* As = lds;
    char* Bs = lds + BM * BK * 2;

    const int tid = threadIdx.x;
    const int l  = tid & 63;
    const int w  = tid >> 6;
    const int wr = w >> 1, wc = w & 1;   // wave grid 2x2 over 128x128 tile
    const int fr = l & 15;               // fragment row/col index
    const int kg = l >> 4;               // k-group (8 contiguous k each)

    const int rowBase = blockIdx.y * BM;
    const int colBase = blockIdx.x * BN;

    f32x4 acc[4][4];
    const f32x4 zero = {0.f, 0.f, 0.f, 0.f};
    #pragma unroll
    for (int mi = 0; mi < 4; mi++)
        #pragma unroll
        for (int ni = 0; ni < 4; ni++)
            acc[mi][ni] = zero;

    const char* gA = (const char*)Xb;
    const char* gB = (const char*)Yb;
    const int rq   = l >> 3;   // row within an 8-row group (1024B per gload)
    const int slot = l & 7;    // 16B slot within a 128B row (BK=64)

    for (int kt = 0; kt < D_DIM / BK; kt++) {
        // ---- stage A and B tiles (pre-swizzled global source, linear LDS) ----
        #pragma unroll
        for (int i = 0; i < 4; i++) {
            int row = w * 32 + i * 8 + rq;
            int gslot = slot ^ (row & 7);
            const void* srcA = gA + ((size_t)(rowBase + row) * D_DIM + kt * BK) * 2 + gslot * 16;
            const void* srcB = gB + ((size_t)(colBase + row) * D_DIM + kt * BK) * 2 + gslot * 16;
            __builtin_amdgcn_global_load_lds(
                (const __attribute__((address_space(1))) void*)srcA,
                (__attribute__((address_space(3))) void*)(As + (w * 32 + i * 8) * 128),
                16, 0, 0);
            __builtin_amdgcn_global_load_lds(
                (const __attribute__((address_space(1))) void*)srcB,
                (__attribute__((address_space(3))) void*)(Bs + (w * 32 + i * 8) * 128),
                16, 0, 0);
        }
        __syncthreads();

        // ---- compute: 2 k-steps of 32, 4x4 fragments ----
        #pragma unroll
        for (int kk = 0; kk < 2; kk++) {
            bf16x8 af[4], bg[4];
            #pragma unroll
            for (int mi = 0; mi < 4; mi++) {
                int row = wr * 64 + mi * 16 + fr;
                int sl = (kk * 4 + kg) ^ (row & 7);
                af[mi] = *(const bf16x8*)(As + row * 128 + sl * 16);
            }
            #pragma unroll
            for (int ni = 0; ni < 4; ni++) {
                int row = wc * 64 + ni * 16 + fr;
                int sl = (kk * 4 + kg) ^ (row & 7);
                bg[ni] = *(const bf16x8*)(Bs + row * 128 + sl * 16);
            }
            #pragma unroll
            for (int mi = 0; mi < 4; mi++)
                #pragma unroll
                for (int ni = 0; ni < 4; ni++)
                    acc[mi][ni] = __builtin_amdgcn_mfma_f32_16x16x32_bf16(
                        af[mi], bg[ni], acc[mi][ni], 0, 0, 0);
        }
        __syncthreads();
    }

    // ---- epilogue: p = exp((s-1)/tau); reduce over columns ----
    // C/D layout (m89/m91 verified): col = lane&15 (fr), row = (lane>>4)*4 + r
    float rp[4][4];  // [mi][r]
    #pragma unroll
    for (int mi = 0; mi < 4; mi++)
        #pragma unroll
        for (int r = 0; r < 4; r++) {
            float s = 0.f;
            #pragma unroll
            for (int ni = 0; ni < 4; ni++)
                s += __expf((acc[mi][ni][r] - 1.0f) * INV_T);
            rp[mi][r] = s;
        }
    // reduce across the 16 columns held by the 16 lanes of each lane-group
    #pragma unroll
    for (int off = 8; off > 0; off >>= 1)
        #pragma unroll
        for (int mi = 0; mi < 4; mi++)
            #pragma unroll
            for (int r = 0; r < 4; r++)
                rp[mi][r] += __shfl_xor(rp[mi][r], off);

    // combine the two column-half waves per row in LDS, then 1 global atomic/row
    float* rowpart = (float*)lds;  // safe: last loop iter ended with barrier
    if (tid < BM) rowpart[tid] = 0.f;
    __syncthreads();
    if (fr == 0) {
        #pragma unroll
        for (int mi = 0; mi < 4; mi++)
            #pragma unroll
            for (int r = 0; r < 4; r++)
                atomicAdd(&rowpart[wr * 64 + mi * 16 + kg * 4 + r], rp[mi][r]);
    }
    __syncthreads();
    if (tid < BM) atomicAdd(&rowsum[rowBase + tid], rowpart[tid]);
}

// ---------------------------------------------------------------------------
// Kernel C: loss = -mean(Sv_i - log(rowsum_i)); single block.
// ---------------------------------------------------------------------------
__global__ __launch_bounds__(256) void lit_finalize(
    const float* __restrict__ Sv, const float* __restrict__ rowsum,
    float* __restrict__ out, int N)
{
    float acc = 0.f;
    for (int i = threadIdx.x; i < N; i += 256)
        acc += Sv[i] - logf(rowsum[i]);
    #pragma unroll
    for (int o = 32; o > 0; o >>= 1) acc += __shfl_down(acc, o);
    __shared__ float sred[4];
    if ((threadIdx.x & 63) == 0) sred[threadIdx.x >> 6] = acc;
    __syncthreads();
    if (threadIdx.x == 0)
        out[0] = -(sred[0] + sred[1] + sred[2] + sred[3]) / (float)N;
}

// ---------------------------------------------------------------------------
extern "C" void kernel_launch(void* const* d_in, const int* in_sizes, int n_in,
                              void* d_out, int out_size, void* d_ws, size_t ws_size,
                              hipStream_t stream)
{
    const float* X = (const float*)d_in[0];
    const float* Y = (const float*)d_in[1];
    const int N = in_sizes[0] / D_DIM;

    char* ws = (char*)d_ws;
    __hip_bfloat16* Xb = (__hip_bfloat16*)ws;                                   // N*D*2 bytes
    __hip_bfloat16* Yb = (__hip_bfloat16*)(ws + (size_t)N * D_DIM * 2);         // N*D*2 bytes
    float* Sv     = (float*)(ws + (size_t)N * D_DIM * 4);                        // N*4
    float* rowsum = (float*)(ws + (size_t)N * D_DIM * 4 + (size_t)N * 4);        // N*4

    lit_normalize<<<N, 256, 0, stream>>>(X, Y, Xb, Yb, Sv, rowsum);
    dim3 grid(N / BN, N / BM);
    lit_gemm_rowsum<<<grid, 256, 0, stream>>>(Xb, Yb, rowsum, N);
    lit_finalize<<<1, 256, 0, stream>>>(Sv, rowsum, (float*)d_out, N);
}

// Round 2
// 265.531 us; speedup vs baseline: 1.1944x; 1.1944x over previous
//
#include <hip/hip_runtime.h>
#include <hip/hip_bf16.h>
#include <stdint.h>

#define D_DIM 256
#define INV_T 14.285714285714286f  // 1/0.07

#define BM 256
#define BN 256
#define BK 64
#define NSTEP (D_DIM / BK)  // 4

typedef __bf16 bf16x8 __attribute__((ext_vector_type(8)));
typedef float f32x16 __attribute__((ext_vector_type(16)));

// ---------------------------------------------------------------------------
// Kernel A: normalization. One wave per row (float4 loads), 4 rows/block.
// Exact fp32 diagonal Sv, bf16 normalized outputs, rowsum & acc1 zero-init.
// ---------------------------------------------------------------------------
__global__ __launch_bounds__(256) void lit_normalize(
    const float* __restrict__ X, const float* __restrict__ Y,
    __hip_bfloat16* __restrict__ Xb, __hip_bfloat16* __restrict__ Yb,
    float* __restrict__ Sv, float* __restrict__ rowsum, float* __restrict__ acc1)
{
    const int l = threadIdx.x & 63;
    const int row = blockIdx.x * 4 + (threadIdx.x >> 6);
    const size_t base = (size_t)row * D_DIM;
    const float4 x = ((const float4*)(X + base))[l];
    const float4 y = ((const float4*)(Y + base))[l];
    float nx = x.x * x.x + x.y * x.y + x.z * x.z + x.w * x.w;
    float ny = y.x * y.x + y.y * y.y + y.z * y.z + y.w * y.w;
    float dt = x.x * y.x + x.y * y.y + x.z * y.z + x.w * y.w;
    #pragma unroll
    for (int o = 1; o < 64; o <<= 1) {
        nx += __shfl_xor(nx, o);
        ny += __shfl_xor(ny, o);
        dt += __shfl_xor(dt, o);
    }
    const float ivx = 1.0f / fmaxf(sqrtf(nx), 1e-12f);
    const float ivy = 1.0f / fmaxf(sqrtf(ny), 1e-12f);

    __hip_bfloat16 hx0 = __float2bfloat16(x.x * ivx), hx1 = __float2bfloat16(x.y * ivx);
    __hip_bfloat16 hx2 = __float2bfloat16(x.z * ivx), hx3 = __float2bfloat16(x.w * ivx);
    __hip_bfloat16 hy0 = __float2bfloat16(y.x * ivy), hy1 = __float2bfloat16(y.y * ivy);
    __hip_bfloat16 hy2 = __float2bfloat16(y.z * ivy), hy3 = __float2bfloat16(y.w * ivy);
    ushort4 px, py;
    px.x = *(unsigned short*)&hx0; px.y = *(unsigned short*)&hx1;
    px.z = *(unsigned short*)&hx2; px.w = *(unsigned short*)&hx3;
    py.x = *(unsigned short*)&hy0; py.y = *(unsigned short*)&hy1;
    py.z = *(unsigned short*)&hy2; py.w = *(unsigned short*)&hy3;
    ((ushort4*)(Xb + base))[l] = px;
    ((ushort4*)(Yb + base))[l] = py;

    if (l == 0) {
        Sv[row] = (dt * ivx * ivy - 1.0f) * INV_T;  // exact diagonal logit
        rowsum[row] = 0.0f;
    }
    if (blockIdx.x == 0 && threadIdx.x == 0) acc1[0] = 0.0f;
}

// ---------------------------------------------------------------------------
// Kernel B: S = Xhat @ Yhat^T with SWAPPED operands: D = mfma(Y_frag, X_frag)
// so D[m=j][n=i] -> the j-reduction (row-sum of exp) is in-thread.
// 256x256 tile, BK=64, 8 waves (2i x 4j), wave tile 128i x 64j,
// 32x32x16 bf16 MFMA, fragments fj in {0,1}, fi in {0..3}.
// LDS: Xs[256][64] | Ys[256][64] bf16 = 64 KB, XOR-swizzled slot realized by
// pre-swizzling the global source for global_load_lds (linear dest, rule #21).
// ---------------------------------------------------------------------------
__global__ __launch_bounds__(512, 2) void lit_gemm_rowsum(
    const __hip_bfloat16* __restrict__ Xb, const __hip_bfloat16* __restrict__ Yb,
    float* __restrict__ rowsum)
{
    __shared__ char lds[BM * BK * 2 + BN * BK * 2];  // 32KB Xs + 32KB Ys

    const int tid = (int)threadIdx.x;
    const int l   = tid & 63;
    const int w   = tid >> 6;    // 0..7
    const int wi  = w >> 2;      // 0..1  (i-half of the tile)
    const int wj  = w & 3;       // 0..3  (j-quarter)

    // XCD-aware bijective swizzle of the 64x64 block grid (nwg % 8 == 0)
    const int nx  = (int)gridDim.x;
    const int bid = (int)blockIdx.y * nx + (int)blockIdx.x;
    const int cpx = (nx * (int)gridDim.y) >> 3;
    const int logical = (bid & 7) * cpx + (bid >> 3);
    const int bi = logical / nx;
    const int bj = logical % nx;
    const int iBase = bi * BM;
    const int jBase = bj * BN;

    f32x16 acc[2][4];
    #pragma unroll
    for (int a = 0; a < 2; ++a)
        #pragma unroll
        for (int b = 0; b < 4; ++b)
            #pragma unroll
            for (int r = 0; r < 16; ++r)
                acc[a][b][r] = 0.f;

    // Staging: 64 chunks of 8 rows x 128B; wave w owns chunks w*8..w*8+7.
    // Chunks 0..31 = X rows 0..255; chunks 32..63 = Y rows 0..255.
    const int rq = l >> 3;   // row within chunk
    const int sl = l & 7;    // 16B slot within a 128B row
    const char* src[8];
    int dst[8];
    #pragma unroll
    for (int c = 0; c < 8; ++c) {
        const int g    = w * 8 + c;
        const int isY  = g >> 5;
        const int r8   = (g & 31) * 8;
        const int row  = r8 + rq;
        const int slot = sl ^ (row & 7);  // pre-swizzled source slot
        const char* base = isY ? (const char*)Yb + (size_t)jBase * (D_DIM * 2)
                               : (const char*)Xb + (size_t)iBase * (D_DIM * 2);
        src[c] = base + (size_t)row * (D_DIM * 2) + slot * 16;
        dst[c] = isY * (BM * BK * 2) + r8 * 128;
    }

    #pragma unroll
    for (int t = 0; t < NSTEP; ++t) {
        #pragma unroll
        for (int c = 0; c < 8; ++c)
            __builtin_amdgcn_global_load_lds(
                (const __attribute__((address_space(1))) void*)(src[c] + t * (BK * 2)),
                (__attribute__((address_space(3))) void*)(lds + dst[c]),
                16, 0, 0);
        __syncthreads();

        const char* Xs = lds;
        const char* Ys = lds + BM * BK * 2;
        #pragma unroll
        for (int kk = 0; kk < 4; ++kk) {
            // 16B slot for this MFMA K-step: k = kk*16 + (l>>5)*8
            const int sx = ((kk * 2 + (l >> 5)) ^ (l & 7)) * 16;
            const int lr = l & 31;
            bf16x8 a0 = *(const bf16x8*)(Ys + (wj * 64 +  0 + lr) * 128 + sx);
            bf16x8 a1 = *(const bf16x8*)(Ys + (wj * 64 + 32 + lr) * 128 + sx);
            bf16x8 b0 = *(const bf16x8*)(Xs + (wi * 128 +  0 + lr) * 128 + sx);
            bf16x8 b1 = *(const bf16x8*)(Xs + (wi * 128 + 32 + lr) * 128 + sx);
            bf16x8 b2 = *(const bf16x8*)(Xs + (wi * 128 + 64 + lr) * 128 + sx);
            bf16x8 b3 = *(const bf16x8*)(Xs + (wi * 128 + 96 + lr) * 128 + sx);
            acc[0][0] = __builtin_amdgcn_mfma_f32_32x32x16_bf16(a0, b0, acc[0][0], 0, 0, 0);
            acc[0][1] = __builtin_amdgcn_mfma_f32_32x32x16_bf16(a0, b1, acc[0][1], 0, 0, 0);
            acc[0][2] = __builtin_amdgcn_mfma_f32_32x32x16_bf16(a0, b2, acc[0][2], 0, 0, 0);
            acc[0][3] = __builtin_amdgcn_mfma_f32_32x32x16_bf16(a0, b3, acc[0][3], 0, 0, 0);
            acc[1][0] = __builtin_amdgcn_mfma_f32_32x32x16_bf16(a1, b0, acc[1][0], 0, 0, 0);
            acc[1][1] = __builtin_amdgcn_mfma_f32_32x32x16_bf16(a1, b1, acc[1][1], 0, 0, 0);
            acc[1][2] = __builtin_amdgcn_mfma_f32_32x32x16_bf16(a1, b2, acc[1][2], 0, 0, 0);
            acc[1][3] = __builtin_amdgcn_mfma_f32_32x32x16_bf16(a1, b3, acc[1][3], 0, 0, 0);
        }
        __syncthreads();
    }

    // ---- epilogue: rowsum_i += sum_j exp((S[i][j]-1)/tau) ----
    // D layout (32x32): n=i = lane&31; m=j = (reg&3) + 8*(reg>>2) + 4*(lane>>5).
    // Sum over j: in-thread over fj and 16 regs, then shfl_xor(32) over lane>>5.
    float part[4];
    #pragma unroll
    for (int fi = 0; fi < 4; ++fi) {
        float s = 0.f;
        #pragma unroll
        for (int fj = 0; fj < 2; ++fj)
            #pragma unroll
            for (int r = 0; r < 16; ++r)
                s += __expf(fmaf(acc[fj][fi][r], INV_T, -INV_T));
        s += __shfl_xor(s, 32);
        part[fi] = s;
    }
    float* rowpart = (float*)lds;  // LDS free after last barrier
    if (tid < BM) rowpart[tid] = 0.f;
    __syncthreads();
    if (l < 32) {
        #pragma unroll
        for (int fi = 0; fi < 4; ++fi)
            atomicAdd(&rowpart[wi * 128 + fi * 32 + l], part[fi]);
    }
    __syncthreads();
    if (tid < BM) atomicAdd(&rowsum[iBase + tid], rowpart[tid]);
}

// ---------------------------------------------------------------------------
// Kernel C1: per-row loss terms, block-reduced, one atomic per block.
// ---------------------------------------------------------------------------
__global__ __launch_bounds__(256) void lit_partial(
    const float* __restrict__ Sv, const float* __restrict__ rowsum,
    float* __restrict__ acc1)
{
    const int i = blockIdx.x * 256 + threadIdx.x;
    float v = Sv[i] - logf(rowsum[i]);
    #pragma unroll
    for (int o = 1; o < 64; o <<= 1) v += __shfl_xor(v, o);
    __shared__ float sred[4];
    if ((threadIdx.x & 63) == 0) sred[threadIdx.x >> 6] = v;
    __syncthreads();
    if (threadIdx.x == 0)
        atomicAdd(acc1, sred[0] + sred[1] + sred[2] + sred[3]);
}

// Kernel C2: scalar finalize.
__global__ void lit_final(const float* __restrict__ acc1, float* __restrict__ out, int N)
{
    out[0] = -acc1[0] / (float)N;
}

// ---------------------------------------------------------------------------
extern "C" void kernel_launch(void* const* d_in, const int* in_sizes, int n_in,
                              void* d_out, int out_size, void* d_ws, size_t ws_size,
                              hipStream_t stream)
{
    const float* X = (const float*)d_in[0];
    const float* Y = (const float*)d_in[1];
    const int N = in_sizes[0] / D_DIM;  // 16384

    char* ws = (char*)d_ws;
    __hip_bfloat16* Xb = (__hip_bfloat16*)ws;
    __hip_bfloat16* Yb = (__hip_bfloat16*)(ws + (size_t)N * D_DIM * 2);
    float* Sv     = (float*)(ws + (size_t)N * D_DIM * 4);
    float* rowsum = (float*)(ws + (size_t)N * D_DIM * 4 + (size_t)N * 4);
    float* acc1   = (float*)(ws + (size_t)N * D_DIM * 4 + (size_t)N * 8);

    lit_normalize<<<N / 4, 256, 0, stream>>>(X, Y, Xb, Yb, Sv, rowsum, acc1);
    dim3 grid(N / BN, N / BM);
    lit_gemm_rowsum<<<grid, 512, 0, stream>>>(Xb, Yb, rowsum);
    lit_partial<<<N / 256, 256, 0, stream>>>(Sv, rowsum, acc1);
    lit_final<<<1, 1, 0, stream>>>(acc1, (float*)d_out, N);
}